// Round 9
// baseline (669.379 us; speedup 1.0000x reference)
//
#include <hip/hip_runtime.h>
#include <math.h>

#define NEG_SLOPE 0.2f

static __device__ __forceinline__ float bf2f(unsigned int hw) {
    return __uint_as_float(hw << 16);
}
static __device__ __forceinline__ float bf2f_lo(unsigned int u) {   // low ushort
    return __uint_as_float(u << 16);
}
static __device__ __forceinline__ float bf2f_hi(unsigned int u) {   // high ushort
    return __uint_as_float(u & 0xffff0000u);
}
static __device__ __forceinline__ unsigned short f2bf(float f) {
    unsigned int u = __float_as_uint(f);
    u += 0x7FFFu + ((u >> 16) & 1u);   // round-to-nearest-even
    return (unsigned short)(u >> 16);
}

// ===========================================================================
// K_A: blocks [0, hist_blocks) run the CSR histogram (8 independent atomics
// per thread for latency ILP; launched FIRST since the latency-bound phase
// is the longer one). Blocks [hist_blocks, ...) run the GEMM with A and W
// tiles staged as bf16 in LDS (25 KB total -> 6 blocks/CU instead of 3, so
// both roles get occupancy). feat packed bf16 to featp[n][d][h].
// ===========================================================================
__global__ __launch_bounds__(256, 5) void k_gemm_hist(
    const float* __restrict__ h, const float* __restrict__ W,
    unsigned short* __restrict__ featp, int N,
    const int* __restrict__ dst, int* __restrict__ cnt, int* __restrict__ pos,
    int E, int hist_blocks)
{
    __shared__ unsigned short As[64 * 68];   //  8704 B (64 k + 4 pad per row)
    __shared__ unsigned short Bs[128 * 64];  // 16384 B, 8B-granule swizzled

    if (blockIdx.x < hist_blocks) {
        // ---- histogram: pos[e] = rank of edge within its dst segment
        int t0 = blockIdx.x * 2048 + threadIdx.x;
#pragma unroll
        for (int q = 0; q < 8; ++q) {
            int e = t0 + q * 256;
            if (e < E) pos[e] = atomicAdd(&cnt[dst[e]], 1);
        }
        return;
    }

    // ---- GEMM: 64x128 block tile, 8 rows x 4 heads per thread
    const int tid = threadIdx.x;
    const int rb = (blockIdx.x - hist_blocks) * 64;
    const int tc = tid & 31;
    const int tr = tid >> 5;

    float acc[8][4];
#pragma unroll
    for (int i = 0; i < 8; ++i)
#pragma unroll
        for (int j = 0; j < 4; ++j) acc[i][j] = 0.0f;

    for (int kch = 0; kch < 2; ++kch) {
        if (kch) __syncthreads();
        // stage A (fp32 -> bf16): 64 rows x 64 k
#pragma unroll
        for (int i = 0; i < 4; ++i) {
            int chunk = i * 256 + tid;
            int r = chunk >> 4;
            int kc = (chunk & 15) << 2;
            int row = rb + r;
            float4 v = make_float4(0.f, 0.f, 0.f, 0.f);
            if (row < N) v = *(const float4*)(h + (size_t)row * 128 + kch * 64 + kc);
            ushort4 pk;
            pk.x = f2bf(v.x); pk.y = f2bf(v.y); pk.z = f2bf(v.z); pk.w = f2bf(v.w);
            *(ushort4*)(As + r * 68 + kc) = pk;
        }
        // stage B (fp32 -> bf16): 128 cols x 64 k, 8B-granule swizzle (&15)
#pragma unroll
        for (int i = 0; i < 8; ++i) {
            int chunk = i * 256 + tid;
            int c = chunk >> 4;
            int kc = (chunk & 15) << 2;
            float4 v = *(const float4*)(W + (size_t)c * 128 + kch * 64 + kc);
            ushort4 pk;
            pk.x = f2bf(v.x); pk.y = f2bf(v.y); pk.z = f2bf(v.z); pk.w = f2bf(v.w);
            int slot = (kc >> 2) ^ (c & 15);
            *(ushort4*)(Bs + (c << 6) + (slot << 2)) = pk;
        }
        __syncthreads();

#pragma unroll 4
        for (int k4 = 0; k4 < 64; k4 += 4) {
            float bx[4][4];
#pragma unroll
            for (int j = 0; j < 4; ++j) {
                int c = tc + 32 * j;
                int slot = (k4 >> 2) ^ (c & 15);
                uint2 u = *(const uint2*)(Bs + (c << 6) + (slot << 2));
                bx[j][0] = bf2f_lo(u.x); bx[j][1] = bf2f_hi(u.x);
                bx[j][2] = bf2f_lo(u.y); bx[j][3] = bf2f_hi(u.y);
            }
#pragma unroll
            for (int i = 0; i < 8; ++i) {
                uint2 u = *(const uint2*)(As + (tr * 8 + i) * 68 + k4);
                float a0 = bf2f_lo(u.x), a1 = bf2f_hi(u.x);
                float a2 = bf2f_lo(u.y), a3 = bf2f_hi(u.y);
#pragma unroll
                for (int j = 0; j < 4; ++j)
                    acc[i][j] += a0 * bx[j][0] + a1 * bx[j][1] +
                                 a2 * bx[j][2] + a3 * bx[j][3];
            }
        }
    }
#pragma unroll
    for (int i = 0; i < 8; ++i) {
        int row = rb + tr * 8 + i;
        if (row < N) {
            ushort4 pk;
            pk.x = f2bf(acc[i][0]);
            pk.y = f2bf(acc[i][1]);
            pk.z = f2bf(acc[i][2]);
            pk.w = f2bf(acc[i][3]);
            *(ushort4*)(featp + (size_t)row * 128 + tc * 4) = pk;
        }
    }
}

// ===========================================================================
// Scans: row = exclusive_scan(cnt)
// ===========================================================================
__global__ void k_scan1(const int* __restrict__ cnt, int* __restrict__ bsum, int N) {
    __shared__ int sd[256];
    int t = threadIdx.x;
    int i = blockIdx.x * 256 + t;
    sd[t] = (i < N) ? cnt[i] : 0;
    __syncthreads();
    for (int s = 128; s > 0; s >>= 1) {
        if (t < s) sd[t] += sd[t + s];
        __syncthreads();
    }
    if (t == 0) bsum[blockIdx.x] = sd[0];
}

__global__ void k_scan2(int* __restrict__ bsum, int nb) {
    __shared__ int sd[1024];
    int t = threadIdx.x;
    sd[t] = (t < nb) ? bsum[t] : 0;
    __syncthreads();
    for (int off = 1; off < 1024; off <<= 1) {
        int add = (t >= off) ? sd[t - off] : 0;
        __syncthreads();
        sd[t] += add;
        __syncthreads();
    }
    if (t < nb) bsum[t] = (t == 0) ? 0 : sd[t - 1];
}

__global__ void k_scan3(const int* __restrict__ cnt, const int* __restrict__ bsum,
                        int* __restrict__ row, int N) {
    __shared__ int sd[256];
    int t = threadIdx.x;
    int i = blockIdx.x * 256 + t;
    int v = (i < N) ? cnt[i] : 0;
    sd[t] = v;
    __syncthreads();
    for (int off = 1; off < 256; off <<= 1) {
        int add = (t >= off) ? sd[t - off] : 0;
        __syncthreads();
        sd[t] += add;
        __syncthreads();
    }
    if (i < N) row[i] = bsum[blockIdx.x] + sd[t] - v;
}

// ===========================================================================
// K_B: blocks [0, scat_blocks) scatter esrc (plain stores); the rest
// compute el/er from packed bf16 feat. Independent work, fused.
// ===========================================================================
__global__ void k_scatter_elr(const int* __restrict__ src, const int* __restrict__ dst,
                              const int* __restrict__ pos, const int* __restrict__ row,
                              int* __restrict__ esrc, int E, int scat_blocks,
                              const unsigned short* __restrict__ featp,
                              const float* __restrict__ attn_l,
                              const float* __restrict__ attn_r,
                              float* __restrict__ el, float* __restrict__ er, int N) {
    if (blockIdx.x < scat_blocks) {
        int e = blockIdx.x * 512 + threadIdx.x;
        if (e < E) esrc[row[dst[e]] + pos[e]] = src[e];
        e += 256;
        if (e < E) esrc[row[dst[e]] + pos[e]] = src[e];
        return;
    }
    int g = (blockIdx.x - scat_blocks) * 256 + threadIdx.x;
    int node = g >> 5;
    int d = g & 31;
    if (node >= N) return;
    uint2 u = *(const uint2*)(featp + (size_t)node * 128 + d * 4);
    float f0 = bf2f_lo(u.x);
    float f1 = bf2f_hi(u.x);
    float f2 = bf2f_lo(u.y);
    float f3 = bf2f_hi(u.y);
    float pl0 = f0 * attn_l[d],      pr0 = f0 * attn_r[d];
    float pl1 = f1 * attn_l[32 + d], pr1 = f1 * attn_r[32 + d];
    float pl2 = f2 * attn_l[64 + d], pr2 = f2 * attn_r[64 + d];
    float pl3 = f3 * attn_l[96 + d], pr3 = f3 * attn_r[96 + d];
#pragma unroll
    for (int m = 1; m < 32; m <<= 1) {
        pl0 += __shfl_xor(pl0, m); pr0 += __shfl_xor(pr0, m);
        pl1 += __shfl_xor(pl1, m); pr1 += __shfl_xor(pr1, m);
        pl2 += __shfl_xor(pl2, m); pr2 += __shfl_xor(pr2, m);
        pl3 += __shfl_xor(pl3, m); pr3 += __shfl_xor(pr3, m);
    }
    if (d == 0) {
        *(float4*)(el + (size_t)node * 4) = make_float4(pl0, pl1, pl2, pl3);
        *(float4*)(er + (size_t)node * 4) = make_float4(pr0, pr1, pr2, pr3);
    }
}

// ===========================================================================
// Pull, phase-split: one wave per dst node, 64-edge chunks.
// Phase A (edge-parallel): lane i owns edge i -> 1 el-gather + 4 exp PER EDGE.
// Phase B: WAVE-UNIFORM trip count (ii even, i = ii + half) so every __shfl
// executes with all 64 lanes active (shfl from exec-masked lanes returns 0
// on CDNA — caused the R6 failure). Phantom edge i==m broadcasts zeros.
// ===========================================================================
__global__ __launch_bounds__(256) void k_pull(const int* __restrict__ esrc,
                                              const int* __restrict__ row,
                                              const int* __restrict__ cnt,
                                              const float* __restrict__ el,
                                              const float* __restrict__ er,
                                              const unsigned short* __restrict__ featp,
                                              const float* __restrict__ bias,
                                              float* __restrict__ out, int N) {
    int wave = (int)((blockIdx.x * (size_t)blockDim.x + threadIdx.x) >> 6);
    if (wave >= N) return;
    int lane = threadIdx.x & 63;
    int half = lane >> 5;
    int d = lane & 31;
    int start = row[wave];
    int deg = cnt[wave];
    float4 r4 = *(const float4*)(er + 4 * (size_t)wave);

    float acc0 = 0.f, acc1 = 0.f, acc2 = 0.f, acc3 = 0.f;
    float dn0 = 0.f, dn1 = 0.f, dn2 = 0.f, dn3 = 0.f;

    for (int base = 0; base < deg; base += 64) {
        int m = deg - base;
        if (m > 64) m = 64;
        // Phase A: lane owns edge base+lane
        int s_mine = 0;
        float a0 = 0.f, a1 = 0.f, a2 = 0.f, a3 = 0.f;
        if (lane < m) {
            s_mine = esrc[start + base + lane];
            float4 l4 = *(const float4*)(el + 4 * (size_t)s_mine);
            float v0 = l4.x + r4.x; v0 = v0 > 0.f ? v0 : NEG_SLOPE * v0;
            float v1 = l4.y + r4.y; v1 = v1 > 0.f ? v1 : NEG_SLOPE * v1;
            float v2 = l4.z + r4.z; v2 = v2 > 0.f ? v2 : NEG_SLOPE * v2;
            float v3 = l4.w + r4.w; v3 = v3 > 0.f ? v3 : NEG_SLOPE * v3;
            a0 = __expf(v0); a1 = __expf(v1); a2 = __expf(v2); a3 = __expf(v3);
            dn0 += a0; dn1 += a1; dn2 += a2; dn3 += a3;
        }
        // Phase B: half 0 takes edge ii, half 1 takes edge ii+1; uniform flow
        for (int ii = 0; ii < m; ii += 2) {
            int i = ii + half;             // <= 63 always (m <= 64, ii even)
            int sj   = __shfl(s_mine, i);
            float b0 = __shfl(a0, i);
            float b1 = __shfl(a1, i);
            float b2 = __shfl(a2, i);
            float b3 = __shfl(a3, i);
            uint2 u = *(const uint2*)(featp + (size_t)sj * 128 + d * 4);
            float f0 = bf2f_lo(u.x);
            float f1 = bf2f_hi(u.x);
            float f2 = bf2f_lo(u.y);
            float f3 = bf2f_hi(u.y);
            acc0 += b0 * f0; acc1 += b1 * f1; acc2 += b2 * f2; acc3 += b3 * f3;
        }
    }
    // acc: lanes d and d+32 hold even/odd-edge partials for dim d
    acc0 += __shfl_xor(acc0, 32); acc1 += __shfl_xor(acc1, 32);
    acc2 += __shfl_xor(acc2, 32); acc3 += __shfl_xor(acc3, 32);
    // dn: per-owner-lane partials across all 64 lanes -> full tree reduce
#pragma unroll
    for (int m = 1; m < 64; m <<= 1) {
        dn0 += __shfl_xor(dn0, m); dn1 += __shfl_xor(dn1, m);
        dn2 += __shfl_xor(dn2, m); dn3 += __shfl_xor(dn3, m);
    }
    if (half == 0) {
        float msum = 0.f;
        if (dn0 > 0.f)
            msum = acc0 / dn0 + acc1 / dn1 + acc2 / dn2 + acc3 / dn3;
        float b = 0.25f * (bias[d] + bias[32 + d] + bias[64 + d] + bias[96 + d]);
        out[(size_t)wave * 32 + d] = 0.25f * msum + b;
    }
}

// ===========================================================================
extern "C" void kernel_launch(void* const* d_in, const int* in_sizes, int n_in,
                              void* d_out, int out_size, void* d_ws, size_t ws_size,
                              hipStream_t stream) {
    const float* h      = (const float*)d_in[0];
    const int*   src    = (const int*)d_in[1];
    const int*   dst    = (const int*)d_in[2];
    const float* W      = (const float*)d_in[4];
    const float* attn_l = (const float*)d_in[5];
    const float* attn_r = (const float*)d_in[6];
    const float* bias   = (const float*)d_in[7];
    float* out = (float*)d_out;

    const int N = in_sizes[0] / 128;
    const int E = in_sizes[1];

    // ws layout: el [N,4] f32 | er [N,4] f32 | featp [N,128] bf16 |
    //            cnt [N] | row [N] | bsum [1024] | pos [E] | esrc [E]
    float* el = (float*)d_ws;
    float* er = el + (size_t)N * 4;
    unsigned short* featp = (unsigned short*)(er + (size_t)N * 4);
    int* cnt  = (int*)(featp + (size_t)N * 128);
    int* row  = cnt + N;
    int* bsum = row + N;
    int* pos  = bsum + 1024;
    int* esrc = pos + E;
    int nb = (N + 255) / 256;  // <= 1024 for N <= 262144

    hipMemsetAsync(cnt, 0, (size_t)N * 4, stream);

    int hist_blocks = (E + 2047) / 2048;         // ILP-8 per thread
    int gemm_blocks = (N + 63) / 64;
    k_gemm_hist<<<hist_blocks + gemm_blocks, 256, 0, stream>>>(
        h, W, featp, N, dst, cnt, pos, E, hist_blocks);

    k_scan1<<<nb, 256, 0, stream>>>(cnt, bsum, N);
    k_scan2<<<1, 1024, 0, stream>>>(bsum, nb);
    k_scan3<<<nb, 256, 0, stream>>>(cnt, bsum, row, N);

    int scat_blocks = (E + 511) / 512;
    int elr_blocks = ((size_t)N * 32 + 255) / 256;
    k_scatter_elr<<<scat_blocks + elr_blocks, 256, 0, stream>>>(
        src, dst, pos, row, esrc, E, scat_blocks,
        featp, attn_l, attn_r, el, er, N);

    k_pull<<<((size_t)N * 64 + 255) / 256, 256, 0, stream>>>(esrc, row, cnt, el, er,
                                                             featp, bias, out, N);
}

// Round 10
// 390.129 us; speedup vs baseline: 1.7158x; 1.7158x over previous
//
#include <hip/hip_runtime.h>
#include <math.h>

#define NEG_SLOPE 0.2f

static __device__ __forceinline__ float bf2f_lo(unsigned int u) {   // low ushort
    return __uint_as_float(u << 16);
}
static __device__ __forceinline__ float bf2f_hi(unsigned int u) {   // high ushort
    return __uint_as_float(u & 0xffff0000u);
}
static __device__ __forceinline__ unsigned short f2bf(float f) {
    unsigned int u = __float_as_uint(f);
    u += 0x7FFFu + ((u >> 16) & 1u);   // round-to-nearest-even
    return (unsigned short)(u >> 16);
}

// ===========================================================================
// K_A: blocks [0, hist_blocks) run the CSR histogram (8 independent atomics
// per thread, launched first: the latency-bound phase is the longer one).
// Blocks [hist_blocks, ...) run the GEMM with A/W tiles staged bf16 in LDS
// (25088 B -> 6 blocks/CU). launch_bounds min-waves/EU = 3 (NOT 5: that
// capped VGPR at 48 and spilled acc[] to scratch -> 900 MB HBM traffic,
// the R9 regression). feat packed bf16 to featp[n][d][h].
// ===========================================================================
__global__ __launch_bounds__(256, 3) void k_gemm_hist(
    const float* __restrict__ h, const float* __restrict__ W,
    unsigned short* __restrict__ featp, int N,
    const int* __restrict__ dst, int* __restrict__ cnt, int* __restrict__ pos,
    int E, int hist_blocks)
{
    __shared__ unsigned short As[64 * 68];   //  8704 B (64 k + 4 pad per row)
    __shared__ unsigned short Bs[128 * 64];  // 16384 B, 8B-granule swizzled

    if (blockIdx.x < hist_blocks) {
        // ---- histogram: pos[e] = rank of edge within its dst segment
        int t0 = blockIdx.x * 2048 + threadIdx.x;
#pragma unroll
        for (int q = 0; q < 8; ++q) {
            int e = t0 + q * 256;
            if (e < E) pos[e] = atomicAdd(&cnt[dst[e]], 1);
        }
        return;
    }

    // ---- GEMM: 64x128 block tile, 8 rows x 4 heads per thread
    const int tid = threadIdx.x;
    const int rb = (blockIdx.x - hist_blocks) * 64;
    const int tc = tid & 31;
    const int tr = tid >> 5;

    float acc[8][4];
#pragma unroll
    for (int i = 0; i < 8; ++i)
#pragma unroll
        for (int j = 0; j < 4; ++j) acc[i][j] = 0.0f;

    for (int kch = 0; kch < 2; ++kch) {
        if (kch) __syncthreads();
        // stage A (fp32 -> bf16): 64 rows x 64 k
#pragma unroll
        for (int i = 0; i < 4; ++i) {
            int chunk = i * 256 + tid;
            int r = chunk >> 4;
            int kc = (chunk & 15) << 2;
            int row = rb + r;
            float4 v = make_float4(0.f, 0.f, 0.f, 0.f);
            if (row < N) v = *(const float4*)(h + (size_t)row * 128 + kch * 64 + kc);
            ushort4 pk;
            pk.x = f2bf(v.x); pk.y = f2bf(v.y); pk.z = f2bf(v.z); pk.w = f2bf(v.w);
            *(ushort4*)(As + r * 68 + kc) = pk;
        }
        // stage B (fp32 -> bf16): 128 cols x 64 k, 8B-granule swizzle (&15)
#pragma unroll
        for (int i = 0; i < 8; ++i) {
            int chunk = i * 256 + tid;
            int c = chunk >> 4;
            int kc = (chunk & 15) << 2;
            float4 v = *(const float4*)(W + (size_t)c * 128 + kch * 64 + kc);
            ushort4 pk;
            pk.x = f2bf(v.x); pk.y = f2bf(v.y); pk.z = f2bf(v.z); pk.w = f2bf(v.w);
            int slot = (kc >> 2) ^ (c & 15);
            *(ushort4*)(Bs + (c << 6) + (slot << 2)) = pk;
        }
        __syncthreads();

#pragma unroll 4
        for (int k4 = 0; k4 < 64; k4 += 4) {
            float bx[4][4];
#pragma unroll
            for (int j = 0; j < 4; ++j) {
                int c = tc + 32 * j;
                int slot = (k4 >> 2) ^ (c & 15);
                uint2 u = *(const uint2*)(Bs + (c << 6) + (slot << 2));
                bx[j][0] = bf2f_lo(u.x); bx[j][1] = bf2f_hi(u.x);
                bx[j][2] = bf2f_lo(u.y); bx[j][3] = bf2f_hi(u.y);
            }
#pragma unroll
            for (int i = 0; i < 8; ++i) {
                uint2 u = *(const uint2*)(As + (tr * 8 + i) * 68 + k4);
                float a0 = bf2f_lo(u.x), a1 = bf2f_hi(u.x);
                float a2 = bf2f_lo(u.y), a3 = bf2f_hi(u.y);
#pragma unroll
                for (int j = 0; j < 4; ++j)
                    acc[i][j] += a0 * bx[j][0] + a1 * bx[j][1] +
                                 a2 * bx[j][2] + a3 * bx[j][3];
            }
        }
    }
#pragma unroll
    for (int i = 0; i < 8; ++i) {
        int row = rb + tr * 8 + i;
        if (row < N) {
            ushort4 pk;
            pk.x = f2bf(acc[i][0]);
            pk.y = f2bf(acc[i][1]);
            pk.z = f2bf(acc[i][2]);
            pk.w = f2bf(acc[i][3]);
            *(ushort4*)(featp + (size_t)row * 128 + tc * 4) = pk;
        }
    }
}

// ===========================================================================
// Scans: row = exclusive_scan(cnt)
// ===========================================================================
__global__ void k_scan1(const int* __restrict__ cnt, int* __restrict__ bsum, int N) {
    __shared__ int sd[256];
    int t = threadIdx.x;
    int i = blockIdx.x * 256 + t;
    sd[t] = (i < N) ? cnt[i] : 0;
    __syncthreads();
    for (int s = 128; s > 0; s >>= 1) {
        if (t < s) sd[t] += sd[t + s];
        __syncthreads();
    }
    if (t == 0) bsum[blockIdx.x] = sd[0];
}

__global__ void k_scan2(int* __restrict__ bsum, int nb) {
    __shared__ int sd[1024];
    int t = threadIdx.x;
    sd[t] = (t < nb) ? bsum[t] : 0;
    __syncthreads();
    for (int off = 1; off < 1024; off <<= 1) {
        int add = (t >= off) ? sd[t - off] : 0;
        __syncthreads();
        sd[t] += add;
        __syncthreads();
    }
    if (t < nb) bsum[t] = (t == 0) ? 0 : sd[t - 1];
}

__global__ void k_scan3(const int* __restrict__ cnt, const int* __restrict__ bsum,
                        int* __restrict__ row, int N) {
    __shared__ int sd[256];
    int t = threadIdx.x;
    int i = blockIdx.x * 256 + t;
    int v = (i < N) ? cnt[i] : 0;
    sd[t] = v;
    __syncthreads();
    for (int off = 1; off < 256; off <<= 1) {
        int add = (t >= off) ? sd[t - off] : 0;
        __syncthreads();
        sd[t] += add;
        __syncthreads();
    }
    if (i < N) row[i] = bsum[blockIdx.x] + sd[t] - v;
}

// ===========================================================================
// K_B: blocks [0, scat_blocks) scatter esrc (plain stores); the rest
// compute el/er from packed bf16 feat. Independent work, fused.
// ===========================================================================
__global__ void k_scatter_elr(const int* __restrict__ src, const int* __restrict__ dst,
                              const int* __restrict__ pos, const int* __restrict__ row,
                              int* __restrict__ esrc, int E, int scat_blocks,
                              const unsigned short* __restrict__ featp,
                              const float* __restrict__ attn_l,
                              const float* __restrict__ attn_r,
                              float* __restrict__ el, float* __restrict__ er, int N) {
    if (blockIdx.x < scat_blocks) {
        int e = blockIdx.x * 512 + threadIdx.x;
        if (e < E) esrc[row[dst[e]] + pos[e]] = src[e];
        e += 256;
        if (e < E) esrc[row[dst[e]] + pos[e]] = src[e];
        return;
    }
    int g = (blockIdx.x - scat_blocks) * 256 + threadIdx.x;
    int node = g >> 5;
    int d = g & 31;
    if (node >= N) return;
    uint2 u = *(const uint2*)(featp + (size_t)node * 128 + d * 4);
    float f0 = bf2f_lo(u.x);
    float f1 = bf2f_hi(u.x);
    float f2 = bf2f_lo(u.y);
    float f3 = bf2f_hi(u.y);
    float pl0 = f0 * attn_l[d],      pr0 = f0 * attn_r[d];
    float pl1 = f1 * attn_l[32 + d], pr1 = f1 * attn_r[32 + d];
    float pl2 = f2 * attn_l[64 + d], pr2 = f2 * attn_r[64 + d];
    float pl3 = f3 * attn_l[96 + d], pr3 = f3 * attn_r[96 + d];
#pragma unroll
    for (int m = 1; m < 32; m <<= 1) {
        pl0 += __shfl_xor(pl0, m); pr0 += __shfl_xor(pr0, m);
        pl1 += __shfl_xor(pl1, m); pr1 += __shfl_xor(pr1, m);
        pl2 += __shfl_xor(pl2, m); pr2 += __shfl_xor(pr2, m);
        pl3 += __shfl_xor(pl3, m); pr3 += __shfl_xor(pr3, m);
    }
    if (d == 0) {
        *(float4*)(el + (size_t)node * 4) = make_float4(pl0, pl1, pl2, pl3);
        *(float4*)(er + (size_t)node * 4) = make_float4(pr0, pr1, pr2, pr3);
    }
}

// ===========================================================================
// Pull, phase-split: one wave per dst node, 64-edge chunks.
// Phase A (edge-parallel): lane i owns edge i -> 1 el-gather + 4 exp PER EDGE.
// Phase B: WAVE-UNIFORM trip count (ii even, i = ii + half) so every __shfl
// executes with all 64 lanes active (shfl from exec-masked lanes returns 0
// on CDNA — caused the R6 failure). Phantom edge i==m broadcasts zeros.
// ===========================================================================
__global__ __launch_bounds__(256) void k_pull(const int* __restrict__ esrc,
                                              const int* __restrict__ row,
                                              const int* __restrict__ cnt,
                                              const float* __restrict__ el,
                                              const float* __restrict__ er,
                                              const unsigned short* __restrict__ featp,
                                              const float* __restrict__ bias,
                                              float* __restrict__ out, int N) {
    int wave = (int)((blockIdx.x * (size_t)blockDim.x + threadIdx.x) >> 6);
    if (wave >= N) return;
    int lane = threadIdx.x & 63;
    int half = lane >> 5;
    int d = lane & 31;
    int start = row[wave];
    int deg = cnt[wave];
    float4 r4 = *(const float4*)(er + 4 * (size_t)wave);

    float acc0 = 0.f, acc1 = 0.f, acc2 = 0.f, acc3 = 0.f;
    float dn0 = 0.f, dn1 = 0.f, dn2 = 0.f, dn3 = 0.f;

    for (int base = 0; base < deg; base += 64) {
        int m = deg - base;
        if (m > 64) m = 64;
        // Phase A: lane owns edge base+lane
        int s_mine = 0;
        float a0 = 0.f, a1 = 0.f, a2 = 0.f, a3 = 0.f;
        if (lane < m) {
            s_mine = esrc[start + base + lane];
            float4 l4 = *(const float4*)(el + 4 * (size_t)s_mine);
            float v0 = l4.x + r4.x; v0 = v0 > 0.f ? v0 : NEG_SLOPE * v0;
            float v1 = l4.y + r4.y; v1 = v1 > 0.f ? v1 : NEG_SLOPE * v1;
            float v2 = l4.z + r4.z; v2 = v2 > 0.f ? v2 : NEG_SLOPE * v2;
            float v3 = l4.w + r4.w; v3 = v3 > 0.f ? v3 : NEG_SLOPE * v3;
            a0 = __expf(v0); a1 = __expf(v1); a2 = __expf(v2); a3 = __expf(v3);
            dn0 += a0; dn1 += a1; dn2 += a2; dn3 += a3;
        }
        // Phase B: half 0 takes edge ii, half 1 takes edge ii+1; uniform flow
        for (int ii = 0; ii < m; ii += 2) {
            int i = ii + half;             // <= 63 always (m <= 64, ii even)
            int sj   = __shfl(s_mine, i);
            float b0 = __shfl(a0, i);
            float b1 = __shfl(a1, i);
            float b2 = __shfl(a2, i);
            float b3 = __shfl(a3, i);
            uint2 u = *(const uint2*)(featp + (size_t)sj * 128 + d * 4);
            float f0 = bf2f_lo(u.x);
            float f1 = bf2f_hi(u.x);
            float f2 = bf2f_lo(u.y);
            float f3 = bf2f_hi(u.y);
            acc0 += b0 * f0; acc1 += b1 * f1; acc2 += b2 * f2; acc3 += b3 * f3;
        }
    }
    // acc: lanes d and d+32 hold even/odd-edge partials for dim d
    acc0 += __shfl_xor(acc0, 32); acc1 += __shfl_xor(acc1, 32);
    acc2 += __shfl_xor(acc2, 32); acc3 += __shfl_xor(acc3, 32);
    // dn: per-owner-lane partials across all 64 lanes -> full tree reduce
#pragma unroll
    for (int m = 1; m < 64; m <<= 1) {
        dn0 += __shfl_xor(dn0, m); dn1 += __shfl_xor(dn1, m);
        dn2 += __shfl_xor(dn2, m); dn3 += __shfl_xor(dn3, m);
    }
    if (half == 0) {
        float msum = 0.f;
        if (dn0 > 0.f)
            msum = acc0 / dn0 + acc1 / dn1 + acc2 / dn2 + acc3 / dn3;
        float b = 0.25f * (bias[d] + bias[32 + d] + bias[64 + d] + bias[96 + d]);
        out[(size_t)wave * 32 + d] = 0.25f * msum + b;
    }
}

// ===========================================================================
extern "C" void kernel_launch(void* const* d_in, const int* in_sizes, int n_in,
                              void* d_out, int out_size, void* d_ws, size_t ws_size,
                              hipStream_t stream) {
    const float* h      = (const float*)d_in[0];
    const int*   src    = (const int*)d_in[1];
    const int*   dst    = (const int*)d_in[2];
    const float* W      = (const float*)d_in[4];
    const float* attn_l = (const float*)d_in[5];
    const float* attn_r = (const float*)d_in[6];
    const float* bias   = (const float*)d_in[7];
    float* out = (float*)d_out;

    const int N = in_sizes[0] / 128;
    const int E = in_sizes[1];

    // ws layout: el [N,4] f32 | er [N,4] f32 | featp [N,128] bf16 |
    //            cnt [N] | row [N] | bsum [1024] | pos [E] | esrc [E]
    float* el = (float*)d_ws;
    float* er = el + (size_t)N * 4;
    unsigned short* featp = (unsigned short*)(er + (size_t)N * 4);
    int* cnt  = (int*)(featp + (size_t)N * 128);
    int* row  = cnt + N;
    int* bsum = row + N;
    int* pos  = bsum + 1024;
    int* esrc = pos + E;
    int nb = (N + 255) / 256;  // <= 1024 for N <= 262144

    hipMemsetAsync(cnt, 0, (size_t)N * 4, stream);

    int hist_blocks = (E + 2047) / 2048;         // ILP-8 per thread
    int gemm_blocks = (N + 63) / 64;
    k_gemm_hist<<<hist_blocks + gemm_blocks, 256, 0, stream>>>(
        h, W, featp, N, dst, cnt, pos, E, hist_blocks);

    k_scan1<<<nb, 256, 0, stream>>>(cnt, bsum, N);
    k_scan2<<<1, 1024, 0, stream>>>(bsum, nb);
    k_scan3<<<nb, 256, 0, stream>>>(cnt, bsum, row, N);

    int scat_blocks = (E + 511) / 512;
    int elr_blocks = ((size_t)N * 32 + 255) / 256;
    k_scatter_elr<<<scat_blocks + elr_blocks, 256, 0, stream>>>(
        src, dst, pos, row, esrc, E, scat_blocks,
        featp, attn_l, attn_r, el, er, N);

    k_pull<<<((size_t)N * 64 + 255) / 256, 256, 0, stream>>>(esrc, row, cnt, el, er,
                                                             featp, bias, out, N);
}

// Round 12
// 344.512 us; speedup vs baseline: 1.9430x; 1.1324x over previous
//
#include <hip/hip_runtime.h>
#include <math.h>

#define NEG_SLOPE 0.2f

typedef short bf16x8 __attribute__((ext_vector_type(8)));
typedef float f32x4 __attribute__((ext_vector_type(4)));

static __device__ __forceinline__ float bf2f_lo(unsigned int u) {
    return __uint_as_float(u << 16);
}
static __device__ __forceinline__ float bf2f_hi(unsigned int u) {
    return __uint_as_float(u & 0xffff0000u);
}
static __device__ __forceinline__ unsigned short f2bf(float f) {
    unsigned int u = __float_as_uint(f);
    u += 0x7FFFu + ((u >> 16) & 1u);   // round-to-nearest-even
    return (unsigned short)(u >> 16);
}

// ===========================================================================
// K_A: blocks [0, hist_blocks): CSR histogram (8 independent device atomics
// per thread — fabric-latency/throughput bound). Blocks [hist_blocks, ...):
// MFMA bf16 GEMM feat = h @ W.T. 64x128 block tile, 4 waves x (16 rows x
// 8 col-tiles), K=128 staged once in LDS as bf16 with ((r&7)<<4) XOR swizzle
// (ds_read_b128 at 2-way bank conflict = free). mfma_f32_16x16x32_bf16:
// A lane: row=l&15, k=(l>>4)*8+j; B: col=l&15, same k; D: col=l&15,
// row=(l>>4)*4+reg (guide-verified layouts). Output packed bf16 to
// featp[n][d][h]. bf16 GEMM inputs proved OK in R10 (absmax 7.8e-3, 3x margin).
// ===========================================================================
__global__ __launch_bounds__(256) void k_gemm_hist(
    const float* __restrict__ h, const float* __restrict__ W,
    unsigned short* __restrict__ featp, int N,
    const int* __restrict__ dst, int* __restrict__ cnt, int* __restrict__ pos,
    int E, int hist_blocks)
{
    __shared__ unsigned short As[64 * 128];   // 16 KB, swizzled
    __shared__ unsigned short Bs[128 * 128];  // 32 KB, swizzled

    if (blockIdx.x < hist_blocks) {
        int t0 = blockIdx.x * 2048 + threadIdx.x;
#pragma unroll
        for (int q = 0; q < 8; ++q) {
            int e = t0 + q * 256;
            if (e < E) pos[e] = atomicAdd(&cnt[dst[e]], 1);
        }
        return;
    }

    const int tid = threadIdx.x;
    const int rb = (blockIdx.x - hist_blocks) * 64;

    // ---- stage A: h[rb..rb+64) x k[0..128) fp32 -> bf16 LDS (swizzled)
#pragma unroll
    for (int i = 0; i < 8; ++i) {
        int chunk = i * 256 + tid;          // 2048 chunks = 64 rows x 32
        int r = chunk >> 5;
        int kc = (chunk & 31) << 2;
        int row = rb + r;
        float4 v = make_float4(0.f, 0.f, 0.f, 0.f);
        if (row < N) v = *(const float4*)(h + (size_t)row * 128 + kc);
        ushort4 pk;
        pk.x = f2bf(v.x); pk.y = f2bf(v.y); pk.z = f2bf(v.z); pk.w = f2bf(v.w);
        int byte = (r << 8) + ((kc << 1) ^ ((r & 7) << 4));
        *(ushort4*)((char*)As + byte) = pk;
    }
    // ---- stage B: W[c][k] fp32 -> bf16 LDS (swizzled); B[k][c] = W[c][k]
#pragma unroll
    for (int i = 0; i < 16; ++i) {
        int chunk = i * 256 + tid;          // 4096 chunks = 128 cols x 32
        int c = chunk >> 5;
        int kc = (chunk & 31) << 2;
        float4 v = *(const float4*)(W + (size_t)c * 128 + kc);
        ushort4 pk;
        pk.x = f2bf(v.x); pk.y = f2bf(v.y); pk.z = f2bf(v.z); pk.w = f2bf(v.w);
        int byte = (c << 8) + ((kc << 1) ^ ((c & 7) << 4));
        *(ushort4*)((char*)Bs + byte) = pk;
    }
    __syncthreads();

    // ---- MFMA compute: wave w owns rows [w*16, w*16+16)
    const int wave = tid >> 6;
    const int lane = tid & 63;
    const int dlo = lane & 15;
    const int kgrp = lane >> 4;             // 0..3
    const int arow = (wave << 4) + dlo;     // LDS A row

    f32x4 acc[8];
#pragma unroll
    for (int t = 0; t < 8; ++t) acc[t] = (f32x4){0.f, 0.f, 0.f, 0.f};

#pragma unroll
    for (int step = 0; step < 4; ++step) {
        int k2 = (step << 6) + (kgrp << 4);   // byte offset of this lane's k0
        bf16x8 a = *(const bf16x8*)((const char*)As +
                    ((arow << 8) + (k2 ^ ((arow & 7) << 4))));
#pragma unroll
        for (int t = 0; t < 8; ++t) {
            int col = (t << 4) + dlo;
            bf16x8 b = *(const bf16x8*)((const char*)Bs +
                        ((col << 8) + (k2 ^ ((col & 7) << 4))));
            acc[t] = __builtin_amdgcn_mfma_f32_16x16x32_bf16(a, b, acc[t], 0, 0, 0);
        }
    }

    // ---- epilogue: D col=l&15 (per tile), row=(l>>4)*4+r. Col c=t*16+dlo
    // -> head = c>>5, d = c&31: even tiles -> d=dlo, odd tiles -> d=dlo+16.
#pragma unroll
    for (int r = 0; r < 4; ++r) {
        int row = rb + (wave << 4) + ((lane >> 4) << 2) + r;
        if (row < N) {
            ushort4 plo, phi;
            plo.x = f2bf(acc[0][r]); plo.y = f2bf(acc[2][r]);
            plo.z = f2bf(acc[4][r]); plo.w = f2bf(acc[6][r]);
            phi.x = f2bf(acc[1][r]); phi.y = f2bf(acc[3][r]);
            phi.z = f2bf(acc[5][r]); phi.w = f2bf(acc[7][r]);
            *(ushort4*)(featp + (size_t)row * 128 + dlo * 4) = plo;
            *(ushort4*)(featp + (size_t)row * 128 + (dlo + 16) * 4) = phi;
        }
    }
}

// ===========================================================================
// Scans: row = exclusive_scan(cnt)
// ===========================================================================
__global__ void k_scan1(const int* __restrict__ cnt, int* __restrict__ bsum, int N) {
    __shared__ int sd[256];
    int t = threadIdx.x;
    int i = blockIdx.x * 256 + t;
    sd[t] = (i < N) ? cnt[i] : 0;
    __syncthreads();
    for (int s = 128; s > 0; s >>= 1) {
        if (t < s) sd[t] += sd[t + s];
        __syncthreads();
    }
    if (t == 0) bsum[blockIdx.x] = sd[0];
}

__global__ void k_scan2(int* __restrict__ bsum, int nb) {
    __shared__ int sd[1024];
    int t = threadIdx.x;
    sd[t] = (t < nb) ? bsum[t] : 0;
    __syncthreads();
    for (int off = 1; off < 1024; off <<= 1) {
        int add = (t >= off) ? sd[t - off] : 0;
        __syncthreads();
        sd[t] += add;
        __syncthreads();
    }
    if (t < nb) bsum[t] = (t == 0) ? 0 : sd[t - 1];
}

__global__ void k_scan3(const int* __restrict__ cnt, const int* __restrict__ bsum,
                        int* __restrict__ row, int N) {
    __shared__ int sd[256];
    int t = threadIdx.x;
    int i = blockIdx.x * 256 + t;
    int v = (i < N) ? cnt[i] : 0;
    sd[t] = v;
    __syncthreads();
    for (int off = 1; off < 256; off <<= 1) {
        int add = (t >= off) ? sd[t - off] : 0;
        __syncthreads();
        sd[t] += add;
        __syncthreads();
    }
    if (i < N) row[i] = bsum[blockIdx.x] + sd[t] - v;
}

// ===========================================================================
// K_B: blocks [0, scat_blocks) scatter esrc (plain stores); the rest
// compute el/er from packed bf16 feat. Independent work, fused.
// ===========================================================================
__global__ void k_scatter_elr(const int* __restrict__ src, const int* __restrict__ dst,
                              const int* __restrict__ pos, const int* __restrict__ row,
                              int* __restrict__ esrc, int E, int scat_blocks,
                              const unsigned short* __restrict__ featp,
                              const float* __restrict__ attn_l,
                              const float* __restrict__ attn_r,
                              float* __restrict__ el, float* __restrict__ er, int N) {
    if (blockIdx.x < scat_blocks) {
        int e = blockIdx.x * 512 + threadIdx.x;
        if (e < E) esrc[row[dst[e]] + pos[e]] = src[e];
        e += 256;
        if (e < E) esrc[row[dst[e]] + pos[e]] = src[e];
        return;
    }
    int g = (blockIdx.x - scat_blocks) * 256 + threadIdx.x;
    int node = g >> 5;
    int d = g & 31;
    if (node >= N) return;
    uint2 u = *(const uint2*)(featp + (size_t)node * 128 + d * 4);
    float f0 = bf2f_lo(u.x);
    float f1 = bf2f_hi(u.x);
    float f2 = bf2f_lo(u.y);
    float f3 = bf2f_hi(u.y);
    float pl0 = f0 * attn_l[d],      pr0 = f0 * attn_r[d];
    float pl1 = f1 * attn_l[32 + d], pr1 = f1 * attn_r[32 + d];
    float pl2 = f2 * attn_l[64 + d], pr2 = f2 * attn_r[64 + d];
    float pl3 = f3 * attn_l[96 + d], pr3 = f3 * attn_r[96 + d];
#pragma unroll
    for (int m = 1; m < 32; m <<= 1) {
        pl0 += __shfl_xor(pl0, m); pr0 += __shfl_xor(pr0, m);
        pl1 += __shfl_xor(pl1, m); pr1 += __shfl_xor(pr1, m);
        pl2 += __shfl_xor(pl2, m); pr2 += __shfl_xor(pr2, m);
        pl3 += __shfl_xor(pl3, m); pr3 += __shfl_xor(pr3, m);
    }
    if (d == 0) {
        *(float4*)(el + (size_t)node * 4) = make_float4(pl0, pl1, pl2, pl3);
        *(float4*)(er + (size_t)node * 4) = make_float4(pr0, pr1, pr2, pr3);
    }
}

// ===========================================================================
// Pull, phase-split: one wave per dst node, 64-edge chunks.
// Phase A (edge-parallel): lane i owns edge i -> 1 el-gather + 4 exp PER EDGE.
// Phase B: WAVE-UNIFORM trip count (ii even, i = ii + half) so every __shfl
// executes with all 64 lanes active (shfl from exec-masked lanes returns 0
// on CDNA — caused the R6 failure). Phantom edge i==m broadcasts zeros.
// ===========================================================================
__global__ __launch_bounds__(256) void k_pull(const int* __restrict__ esrc,
                                              const int* __restrict__ row,
                                              const int* __restrict__ cnt,
                                              const float* __restrict__ el,
                                              const float* __restrict__ er,
                                              const unsigned short* __restrict__ featp,
                                              const float* __restrict__ bias,
                                              float* __restrict__ out, int N) {
    int wave = (int)((blockIdx.x * (size_t)blockDim.x + threadIdx.x) >> 6);
    if (wave >= N) return;
    int lane = threadIdx.x & 63;
    int half = lane >> 5;
    int d = lane & 31;
    int start = row[wave];
    int deg = cnt[wave];
    float4 r4 = *(const float4*)(er + 4 * (size_t)wave);

    float acc0 = 0.f, acc1 = 0.f, acc2 = 0.f, acc3 = 0.f;
    float dn0 = 0.f, dn1 = 0.f, dn2 = 0.f, dn3 = 0.f;

    for (int base = 0; base < deg; base += 64) {
        int m = deg - base;
        if (m > 64) m = 64;
        // Phase A: lane owns edge base+lane
        int s_mine = 0;
        float a0 = 0.f, a1 = 0.f, a2 = 0.f, a3 = 0.f;
        if (lane < m) {
            s_mine = esrc[start + base + lane];
            float4 l4 = *(const float4*)(el + 4 * (size_t)s_mine);
            float v0 = l4.x + r4.x; v0 = v0 > 0.f ? v0 : NEG_SLOPE * v0;
            float v1 = l4.y + r4.y; v1 = v1 > 0.f ? v1 : NEG_SLOPE * v1;
            float v2 = l4.z + r4.z; v2 = v2 > 0.f ? v2 : NEG_SLOPE * v2;
            float v3 = l4.w + r4.w; v3 = v3 > 0.f ? v3 : NEG_SLOPE * v3;
            a0 = __expf(v0); a1 = __expf(v1); a2 = __expf(v2); a3 = __expf(v3);
            dn0 += a0; dn1 += a1; dn2 += a2; dn3 += a3;
        }
        // Phase B: half 0 takes edge ii, half 1 takes edge ii+1; uniform flow
        for (int ii = 0; ii < m; ii += 2) {
            int i = ii + half;             // <= 63 always (m <= 64, ii even)
            int sj   = __shfl(s_mine, i);
            float b0 = __shfl(a0, i);
            float b1 = __shfl(a1, i);
            float b2 = __shfl(a2, i);
            float b3 = __shfl(a3, i);
            uint2 u = *(const uint2*)(featp + (size_t)sj * 128 + d * 4);
            float f0 = bf2f_lo(u.x);
            float f1 = bf2f_hi(u.x);
            float f2 = bf2f_lo(u.y);
            float f3 = bf2f_hi(u.y);
            acc0 += b0 * f0; acc1 += b1 * f1; acc2 += b2 * f2; acc3 += b3 * f3;
        }
    }
    // acc: lanes d and d+32 hold even/odd-edge partials for dim d
    acc0 += __shfl_xor(acc0, 32); acc1 += __shfl_xor(acc1, 32);
    acc2 += __shfl_xor(acc2, 32); acc3 += __shfl_xor(acc3, 32);
    // dn: per-owner-lane partials across all 64 lanes -> full tree reduce
#pragma unroll
    for (int m = 1; m < 64; m <<= 1) {
        dn0 += __shfl_xor(dn0, m); dn1 += __shfl_xor(dn1, m);
        dn2 += __shfl_xor(dn2, m); dn3 += __shfl_xor(dn3, m);
    }
    if (half == 0) {
        float msum = 0.f;
        if (dn0 > 0.f)
            msum = acc0 / dn0 + acc1 / dn1 + acc2 / dn2 + acc3 / dn3;
        float b = 0.25f * (bias[d] + bias[32 + d] + bias[64 + d] + bias[96 + d]);
        out[(size_t)wave * 32 + d] = 0.25f * msum + b;
    }
}

// ===========================================================================
extern "C" void kernel_launch(void* const* d_in, const int* in_sizes, int n_in,
                              void* d_out, int out_size, void* d_ws, size_t ws_size,
                              hipStream_t stream) {
    const float* h      = (const float*)d_in[0];
    const int*   src    = (const int*)d_in[1];
    const int*   dst    = (const int*)d_in[2];
    const float* W      = (const float*)d_in[4];
    const float* attn_l = (const float*)d_in[5];
    const float* attn_r = (const float*)d_in[6];
    const float* bias   = (const float*)d_in[7];
    float* out = (float*)d_out;

    const int N = in_sizes[0] / 128;
    const int E = in_sizes[1];

    // ws layout: el [N,4] f32 | er [N,4] f32 | featp [N,128] bf16 |
    //            cnt [N] | row [N] | bsum [1024] | pos [E] | esrc [E]
    float* el = (float*)d_ws;
    float* er = el + (size_t)N * 4;
    unsigned short* featp = (unsigned short*)(er + (size_t)N * 4);
    int* cnt  = (int*)(featp + (size_t)N * 128);
    int* row  = cnt + N;
    int* bsum = row + N;
    int* pos  = bsum + 1024;
    int* esrc = pos + E;
    int nb = (N + 255) / 256;  // <= 1024 for N <= 262144

    hipMemsetAsync(cnt, 0, (size_t)N * 4, stream);

    int hist_blocks = (E + 2047) / 2048;         // ILP-8 per thread
    int gemm_blocks = (N + 63) / 64;
    k_gemm_hist<<<hist_blocks + gemm_blocks, 256, 0, stream>>>(
        h, W, featp, N, dst, cnt, pos, E, hist_blocks);

    k_scan1<<<nb, 256, 0, stream>>>(cnt, bsum, N);
    k_scan2<<<1, 1024, 0, stream>>>(bsum, nb);
    k_scan3<<<nb, 256, 0, stream>>>(cnt, bsum, row, N);

    int scat_blocks = (E + 511) / 512;
    int elr_blocks = ((size_t)N * 32 + 255) / 256;
    k_scatter_elr<<<scat_blocks + elr_blocks, 256, 0, stream>>>(
        src, dst, pos, row, esrc, E, scat_blocks,
        featp, attn_l, attn_r, el, er, N);

    k_pull<<<((size_t)N * 64 + 255) / 256, 256, 0, stream>>>(esrc, row, cnt, el, er,
                                                             featp, bias, out, N);
}